// Round 3
// baseline (945.173 us; speedup 1.0000x reference)
//
#include <hip/hip_runtime.h>

#define HD   2048
#define FD   1024
#define NEXP 32
#define TOPK 6
#define TT   2048
#define SDIM 2048
#define NPAIR (TT*TOPK)

typedef __bf16 bf16x8 __attribute__((ext_vector_type(8)));
typedef float  f32x4  __attribute__((ext_vector_type(4)));

#define GLOAD_LDS16(g, l) __builtin_amdgcn_global_load_lds( \
    (const __attribute__((address_space(1))) void*)(g),     \
    (__attribute__((address_space(3))) void*)(l), 16, 0, 0)

__device__ __forceinline__ ushort f2b(float f) {
  __bf16 h = (__bf16)f;                 // native cast -> v_cvt_pk_bf16_f32 pairs
  union { __bf16 h; ushort u; } v; v.h = h;
  return v.u;
}

// ---------------- gating (fp32 exact) ----------------
__device__ __forceinline__ void argmax32(float &v, int &i) {
  #pragma unroll
  for (int m = 16; m >= 1; m >>= 1) {
    float ov = __shfl_xor(v, m, 32);
    int   oi = __shfl_xor(i, m, 32);
    if (ov > v || (ov == v && oi < i)) { v = ov; i = oi; }
  }
}

__global__ __launch_bounds__(64) void gating_kernel(
    const float* __restrict__ x, const float* __restrict__ wgate,
    int* __restrict__ topk_idx, float* __restrict__ topk_w, int* __restrict__ cnt)
{
  int t = blockIdx.x;
  int l = threadIdx.x;
  int e = l & 31;
  int half = l >> 5;
  const float* xr = x + (size_t)t * HD + half * (HD/2);
  const float* wr = wgate + (size_t)e * HD + half * (HD/2);
  float acc = 0.f;
  for (int i = 0; i < HD/2; i += 4) {
    float4 a = *(const float4*)(xr + i);
    float4 b = *(const float4*)(wr + i);
    acc += a.x*b.x + a.y*b.y + a.z*b.z + a.w*b.w;
  }
  acc += __shfl_xor(acc, 32);
  float logit = acc;
  float mx = logit;
  #pragma unroll
  for (int m = 16; m >= 1; m >>= 1) mx = fmaxf(mx, __shfl_xor(mx, m, 32));
  float p = __expf(logit - mx);
  float s = p;
  #pragma unroll
  for (int m = 16; m >= 1; m >>= 1) s += __shfl_xor(s, m, 32);
  float score = p / s;
  float gs = score;
  gs = fmaxf(gs, __shfl_xor(gs, 1, 32));
  gs = fmaxf(gs, __shfl_xor(gs, 2, 32));
  int g = e >> 2;
  float gw = gs;
  bool ingroup = false;
  for (int r = 0; r < 3; ++r) {
    float v = gw; int gi = g;
    argmax32(v, gi);
    if (g == gi) { ingroup = true; gw = -1.f; }
  }
  float ms = ingroup ? score : 0.f;
  int myrank = -1;
  float denom = 1e-20f;
  float mw = ms;
  for (int r = 0; r < 6; ++r) {
    float v = mw; int ei = e;
    argmax32(v, ei);
    denom += v;
    if (e == ei) { myrank = r; mw = -1.f; }
  }
  if (l < 32 && myrank >= 0) {
    topk_idx[t*TOPK + myrank] = e;
    topk_w  [t*TOPK + myrank] = score / denom;
    atomicAdd(&cnt[e], 1);
  }
}

__global__ void scan_kernel(const int* __restrict__ cnt, int* __restrict__ offs) {
  if (threadIdx.x == 0) {
    int o = 0;
    for (int e = 0; e < NEXP; ++e) { offs[e] = o; o += cnt[e]; }
  }
}

__global__ void fill_kernel(const int* __restrict__ topk_idx, const float* __restrict__ topk_w,
                            const int* __restrict__ offs, int* __restrict__ cur,
                            int* __restrict__ pair_tok, float* __restrict__ pair_w)
{
  int idx = blockIdx.x * blockDim.x + threadIdx.x;
  if (idx >= NPAIR) return;
  int e = topk_idx[idx];
  int p = offs[e] + atomicAdd(&cur[e], 1);
  pair_tok[p] = idx / TOPK;
  pair_w[p]   = topk_w[idx];
}

__global__ void cvt_kernel(const float* __restrict__ x, ushort* __restrict__ xb) {
  int i = blockIdx.x * blockDim.x + threadIdx.x;
  float4 v = ((const float4*)x)[i];
  ((ushort4*)xb)[i] = make_ushort4(f2b(v.x), f2b(v.y), f2b(v.z), f2b(v.w));
}

// B-tile LDS addressing: [rows][32 k] bf16 (64B/row), 16B k-chunk XOR-swizzled by (row&3).
// write 8B piece: chunk16' = (hg>>1)^(row&3), half = hg&1
// read 16B:       chunk16' = lg^(row&3)
__device__ __forceinline__ int b_woff(int row, int hg) {
  return row*32 + (((hg>>1) ^ (row&3))*8) + (hg&1)*4;
}
__device__ __forceinline__ int b_roff(int row, int lg) {
  return row*32 + ((lg ^ (row&3))*8);
}

// ---------------- routed gate+up: BM=128 BN=64(x2) BK=32, dbuf ----------------
__global__ __launch_bounds__(256) void gu_routed(
    const ushort* __restrict__ xb, const float* __restrict__ wg, const float* __restrict__ wu,
    const int* __restrict__ pair_tok, const float* __restrict__ pair_w,
    const int* __restrict__ cnt, const int* __restrict__ offs,
    ushort* __restrict__ act)
{
  __shared__ ushort A[2][128*32];
  __shared__ ushort Bg[2][64*32];
  __shared__ ushort Bu[2][64*32];

  int bid = blockIdx.x;
  int wid = (bid & 7) * 1024 + (bid >> 3);   // XCD chunk swizzle (8192/8)
  int mt = wid & 15;
  int nt = (wid >> 4) & 15;
  int e  = wid >> 8;
  int ce = cnt[e];
  int m0 = mt * 128;
  if (m0 >= ce) return;
  int oe = offs[e];
  int n0 = nt * 64;
  int tid = threadIdx.x, lane = tid & 63, w = tid >> 6;

  int csrc = (lane & 3) ^ ((lane >> 3) & 3);
  const ushort* asrc[2];
  #pragma unroll
  for (int j = 0; j < 2; ++j) {
    int r = (2*w + j)*16 + (lane >> 2);
    int pi = min(m0 + r, ce - 1);
    asrc[j] = xb + (size_t)pair_tok[oe + pi] * HD + csrc * 8;
  }
  int tsel = tid >> 7;
  int ttb = tid & 127;
  int fg = ttb & 15, hg = ttb >> 4;
  const float* wsrc = (tsel ? wu : wg) + (size_t)e * HD * FD + (size_t)hg*4*FD + n0 + fg*4;

  int lm = lane & 15, lg = lane >> 4;
  int wr = w >> 1, wc = w & 1;
  int asw = (lm >> 1) & 3;

  f32x4 accg[4][2], accu[4][2];
  #pragma unroll
  for (int m = 0; m < 4; ++m)
    #pragma unroll
    for (int n = 0; n < 2; ++n) { accg[m][n] = f32x4{0,0,0,0}; accu[m][n] = f32x4{0,0,0,0}; }

  float4 rB[4];
  #define GU_ISSUE(T, BUF) do { \
    _Pragma("unroll") \
    for (int j = 0; j < 2; ++j) \
      GLOAD_LDS16(asrc[j] + (T)*32, &A[BUF][(2*w+j)*512]); \
    const float* p = wsrc + (size_t)(T)*32*FD; \
    rB[0] = *(const float4*)(p); \
    rB[1] = *(const float4*)(p + FD); \
    rB[2] = *(const float4*)(p + 2*FD); \
    rB[3] = *(const float4*)(p + 3*FD); \
  } while (0)
  #define GU_WRITE(BUF) do { \
    ushort* dst = tsel ? &Bu[BUF][0] : &Bg[BUF][0]; \
    _Pragma("unroll") \
    for (int c = 0; c < 4; ++c) { \
      int row = fg*4 + c; \
      *(ushort4*)&dst[b_woff(row, hg)] = \
        make_ushort4(f2b(rB[0][c]), f2b(rB[1][c]), f2b(rB[2][c]), f2b(rB[3][c])); \
    } \
  } while (0)

  GU_ISSUE(0, 0);
  asm volatile("s_waitcnt vmcnt(0)" ::: "memory");
  GU_WRITE(0);
  __syncthreads();

  int cur = 0;
  for (int t = 0; t < HD/32; ++t) {
    if (t + 1 < HD/32) GU_ISSUE(t + 1, cur ^ 1);
    bf16x8 a[4], bg[2], bu[2];
    #pragma unroll
    for (int m = 0; m < 4; ++m)
      a[m] = *(const bf16x8*)&A[cur][(wr*64 + m*16 + lm)*32 + (lg ^ asw)*8];
    #pragma unroll
    for (int n = 0; n < 2; ++n) {
      int row = wc*32 + n*16 + lm;
      bg[n] = *(const bf16x8*)&Bg[cur][b_roff(row, lg)];
      bu[n] = *(const bf16x8*)&Bu[cur][b_roff(row, lg)];
    }
    #pragma unroll
    for (int m = 0; m < 4; ++m)
      #pragma unroll
      for (int n = 0; n < 2; ++n) {
        accg[m][n] = __builtin_amdgcn_mfma_f32_16x16x32_bf16(a[m], bg[n], accg[m][n], 0, 0, 0);
        accu[m][n] = __builtin_amdgcn_mfma_f32_16x16x32_bf16(a[m], bu[n], accu[m][n], 0, 0, 0);
      }
    if (t + 1 < HD/32) {
      asm volatile("s_waitcnt vmcnt(0)" ::: "memory");
      GU_WRITE(cur ^ 1);
    }
    __syncthreads();
    cur ^= 1;
  }
  #undef GU_ISSUE
  #undef GU_WRITE

  #pragma unroll
  for (int m = 0; m < 4; ++m) {
    #pragma unroll
    for (int j = 0; j < 4; ++j) {
      int rl = wr*64 + m*16 + lg*4 + j;
      int pi = m0 + rl;
      if (pi >= ce) continue;
      float pwv = pair_w[oe + pi];
      size_t base = (size_t)(oe + pi) * FD + n0 + wc*32;
      #pragma unroll
      for (int n = 0; n < 2; ++n) {
        float gv = accg[m][n][j];
        float uv = accu[m][n][j];
        float sv = gv / (1.f + __expf(-gv));
        act[base + n*16 + lm] = f2b(sv * uv * pwv);
      }
    }
  }
}

// ---------------- routed down: BM=128 BN=128 BK=32, dbuf, atomic scatter ----------------
__global__ __launch_bounds__(256) void down_routed(
    const ushort* __restrict__ act, const float* __restrict__ wd,
    const int* __restrict__ pair_tok, const int* __restrict__ cnt, const int* __restrict__ offs,
    float* __restrict__ y)
{
  __shared__ ushort A[2][128*32];
  __shared__ ushort Bd[2][128*32];

  int bid = blockIdx.x;
  int wid = (bid & 7) * 1024 + (bid >> 3);
  int mt = wid & 15;
  int nt = (wid >> 4) & 15;
  int e  = wid >> 8;
  int ce = cnt[e];
  int m0 = mt * 128;
  if (m0 >= ce) return;
  int oe = offs[e];
  int n0 = nt * 128;
  int tid = threadIdx.x, lane = tid & 63, w = tid >> 6;

  int csrc = (lane & 3) ^ ((lane >> 3) & 3);
  const ushort* asrc[2];
  #pragma unroll
  for (int j = 0; j < 2; ++j) {
    int r = (2*w + j)*16 + (lane >> 2);
    int pi = min(m0 + r, ce - 1);
    asrc[j] = act + (size_t)(oe + pi) * FD + csrc * 8;
  }
  int fg = tid & 31, hg = tid >> 5;
  const float* wsrc = wd + (size_t)e * FD * HD + (size_t)hg*4*HD + n0 + fg*4;

  int lm = lane & 15, lg = lane >> 4;
  int wr = w >> 1, wc = w & 1;
  int asw = (lm >> 1) & 3;

  f32x4 acc[4][4];
  #pragma unroll
  for (int m = 0; m < 4; ++m)
    #pragma unroll
    for (int n = 0; n < 4; ++n) acc[m][n] = f32x4{0,0,0,0};

  float4 rB[4];
  #define DN_ISSUE(T, BUF) do { \
    _Pragma("unroll") \
    for (int j = 0; j < 2; ++j) \
      GLOAD_LDS16(asrc[j] + (T)*32, &A[BUF][(2*w+j)*512]); \
    const float* p = wsrc + (size_t)(T)*32*HD; \
    rB[0] = *(const float4*)(p); \
    rB[1] = *(const float4*)(p + HD); \
    rB[2] = *(const float4*)(p + 2*HD); \
    rB[3] = *(const float4*)(p + 3*HD); \
  } while (0)
  #define DN_WRITE(BUF) do { \
    _Pragma("unroll") \
    for (int c = 0; c < 4; ++c) { \
      int row = fg*4 + c; \
      *(ushort4*)&Bd[BUF][b_woff(row, hg)] = \
        make_ushort4(f2b(rB[0][c]), f2b(rB[1][c]), f2b(rB[2][c]), f2b(rB[3][c])); \
    } \
  } while (0)

  DN_ISSUE(0, 0);
  asm volatile("s_waitcnt vmcnt(0)" ::: "memory");
  DN_WRITE(0);
  __syncthreads();

  int cur = 0;
  for (int t = 0; t < FD/32; ++t) {
    if (t + 1 < FD/32) DN_ISSUE(t + 1, cur ^ 1);
    bf16x8 a[4], b[4];
    #pragma unroll
    for (int m = 0; m < 4; ++m)
      a[m] = *(const bf16x8*)&A[cur][(wr*64 + m*16 + lm)*32 + (lg ^ asw)*8];
    #pragma unroll
    for (int n = 0; n < 4; ++n) {
      int row = wc*64 + n*16 + lm;
      b[n] = *(const bf16x8*)&Bd[cur][b_roff(row, lg)];
    }
    #pragma unroll
    for (int m = 0; m < 4; ++m)
      #pragma unroll
      for (int n = 0; n < 4; ++n)
        acc[m][n] = __builtin_amdgcn_mfma_f32_16x16x32_bf16(a[m], b[n], acc[m][n], 0, 0, 0);
    if (t + 1 < FD/32) {
      asm volatile("s_waitcnt vmcnt(0)" ::: "memory");
      DN_WRITE(cur ^ 1);
    }
    __syncthreads();
    cur ^= 1;
  }
  #undef DN_ISSUE
  #undef DN_WRITE

  #pragma unroll
  for (int m = 0; m < 4; ++m) {
    #pragma unroll
    for (int j = 0; j < 4; ++j) {
      int rl = wr*64 + m*16 + lg*4 + j;
      int pi = m0 + rl;
      if (pi >= ce) continue;
      int tok = pair_tok[oe + pi];
      size_t base = (size_t)tok * HD + n0 + wc*64;
      #pragma unroll
      for (int n = 0; n < 4; ++n)
        atomicAdd(&y[base + n*16 + lm], acc[m][n][j]);
    }
  }
}

// ---------------- shared gate+up: BM=128 BN=64(x2) BK=32, dbuf ----------------
__global__ __launch_bounds__(256) void shared_gu(
    const ushort* __restrict__ xb, const float* __restrict__ sg, const float* __restrict__ su,
    ushort* __restrict__ sact)
{
  __shared__ ushort A[2][128*32];
  __shared__ ushort Bg[2][64*32];
  __shared__ ushort Bu[2][64*32];

  int bid = blockIdx.x;
  int wid = (bid & 7) * 64 + (bid >> 3);
  int mt = wid & 15;
  int nt = wid >> 4;
  int m0 = mt * 128;
  int n0 = nt * 64;
  int tid = threadIdx.x, lane = tid & 63, w = tid >> 6;

  int csrc = (lane & 3) ^ ((lane >> 3) & 3);
  const ushort* asrc[2];
  #pragma unroll
  for (int j = 0; j < 2; ++j) {
    int r = (2*w + j)*16 + (lane >> 2);
    asrc[j] = xb + (size_t)(m0 + r) * HD + csrc * 8;
  }
  int tsel = tid >> 7;
  int ttb = tid & 127;
  int bn = ttb >> 1, bsub = ttb & 1;       // row (n), k-half of 16 floats
  const float* bsrc = (tsel ? su : sg) + (size_t)(n0 + bn) * HD + bsub * 16;

  int lm = lane & 15, lg = lane >> 4;
  int wr = w >> 1, wc = w & 1;
  int asw = (lm >> 1) & 3;

  f32x4 accg[4][2], accu[4][2];
  #pragma unroll
  for (int m = 0; m < 4; ++m)
    #pragma unroll
    for (int n = 0; n < 2; ++n) { accg[m][n] = f32x4{0,0,0,0}; accu[m][n] = f32x4{0,0,0,0}; }

  float4 rB[4];
  #define SG_ISSUE(T, BUF) do { \
    _Pragma("unroll") \
    for (int j = 0; j < 2; ++j) \
      GLOAD_LDS16(asrc[j] + (T)*32, &A[BUF][(2*w+j)*512]); \
    const float* p = bsrc + (T)*32; \
    rB[0] = *(const float4*)(p); \
    rB[1] = *(const float4*)(p + 4); \
    rB[2] = *(const float4*)(p + 8); \
    rB[3] = *(const float4*)(p + 12); \
  } while (0)
  // thread writes 16 ushorts (k = bsub*16..+15) as 4x 8B pieces, hg8 = bsub*4+q
  #define SG_WRITE(BUF) do { \
    ushort* dst = tsel ? &Bu[BUF][0] : &Bg[BUF][0]; \
    _Pragma("unroll") \
    for (int q = 0; q < 4; ++q) { \
      int hg8 = bsub*4 + q; \
      *(ushort4*)&dst[b_woff(bn, hg8)] = \
        make_ushort4(f2b(rB[q][0]), f2b(rB[q][1]), f2b(rB[q][2]), f2b(rB[q][3])); \
    } \
  } while (0)

  SG_ISSUE(0, 0);
  asm volatile("s_waitcnt vmcnt(0)" ::: "memory");
  SG_WRITE(0);
  __syncthreads();

  int cur = 0;
  for (int t = 0; t < HD/32; ++t) {
    if (t + 1 < HD/32) SG_ISSUE(t + 1, cur ^ 1);
    bf16x8 a[4], bg[2], bu[2];
    #pragma unroll
    for (int m = 0; m < 4; ++m)
      a[m] = *(const bf16x8*)&A[cur][(wr*64 + m*16 + lm)*32 + (lg ^ asw)*8];
    #pragma unroll
    for (int n = 0; n < 2; ++n) {
      int row = wc*32 + n*16 + lm;
      bg[n] = *(const bf16x8*)&Bg[cur][b_roff(row, lg)];
      bu[n] = *(const bf16x8*)&Bu[cur][b_roff(row, lg)];
    }
    #pragma unroll
    for (int m = 0; m < 4; ++m)
      #pragma unroll
      for (int n = 0; n < 2; ++n) {
        accg[m][n] = __builtin_amdgcn_mfma_f32_16x16x32_bf16(a[m], bg[n], accg[m][n], 0, 0, 0);
        accu[m][n] = __builtin_amdgcn_mfma_f32_16x16x32_bf16(a[m], bu[n], accu[m][n], 0, 0, 0);
      }
    if (t + 1 < HD/32) {
      asm volatile("s_waitcnt vmcnt(0)" ::: "memory");
      SG_WRITE(cur ^ 1);
    }
    __syncthreads();
    cur ^= 1;
  }
  #undef SG_ISSUE
  #undef SG_WRITE

  #pragma unroll
  for (int m = 0; m < 4; ++m) {
    #pragma unroll
    for (int j = 0; j < 4; ++j) {
      int rl = wr*64 + m*16 + lg*4 + j;
      size_t base = (size_t)(m0 + rl) * SDIM + n0 + wc*32;
      #pragma unroll
      for (int n = 0; n < 2; ++n) {
        float gv = accg[m][n][j];
        float uv = accu[m][n][j];
        float sv = gv / (1.f + __expf(-gv));
        sact[base + n*16 + lm] = f2b(sv * uv);
      }
    }
  }
}

// ---------------- shared down: BM=128 BN=128 BK=32, dbuf, y += ----------------
__global__ __launch_bounds__(256) void shared_down(
    const ushort* __restrict__ sact, const float* __restrict__ sd, float* __restrict__ y)
{
  __shared__ ushort A[2][128*32];
  __shared__ ushort Bd[2][128*32];

  int bid = blockIdx.x;
  int wid = (bid & 7) * 32 + (bid >> 3);
  int mt = wid & 15;
  int nt = wid >> 4;
  int m0 = mt * 128;
  int n0 = nt * 128;
  int tid = threadIdx.x, lane = tid & 63, w = tid >> 6;

  int csrc = (lane & 3) ^ ((lane >> 3) & 3);
  const ushort* asrc[2];
  #pragma unroll
  for (int j = 0; j < 2; ++j) {
    int r = (2*w + j)*16 + (lane >> 2);
    asrc[j] = sact + (size_t)(m0 + r) * SDIM + csrc * 8;
  }
  int bn = tid >> 1, bsub = tid & 1;
  const float* bsrc = sd + (size_t)(n0 + bn) * SDIM + bsub * 16;

  int lm = lane & 15, lg = lane >> 4;
  int wr = w >> 1, wc = w & 1;
  int asw = (lm >> 1) & 3;

  f32x4 acc[4][4];
  #pragma unroll
  for (int m = 0; m < 4; ++m)
    #pragma unroll
    for (int n = 0; n < 4; ++n) acc[m][n] = f32x4{0,0,0,0};

  float4 rB[4];
  #define SD_ISSUE(T, BUF) do { \
    _Pragma("unroll") \
    for (int j = 0; j < 2; ++j) \
      GLOAD_LDS16(asrc[j] + (T)*32, &A[BUF][(2*w+j)*512]); \
    const float* p = bsrc + (T)*32; \
    rB[0] = *(const float4*)(p); \
    rB[1] = *(const float4*)(p + 4); \
    rB[2] = *(const float4*)(p + 8); \
    rB[3] = *(const float4*)(p + 12); \
  } while (0)
  #define SD_WRITE(BUF) do { \
    _Pragma("unroll") \
    for (int q = 0; q < 4; ++q) { \
      int hg8 = bsub*4 + q; \
      *(ushort4*)&Bd[BUF][b_woff(bn, hg8)] = \
        make_ushort4(f2b(rB[q][0]), f2b(rB[q][1]), f2b(rB[q][2]), f2b(rB[q][3])); \
    } \
  } while (0)

  SD_ISSUE(0, 0);
  asm volatile("s_waitcnt vmcnt(0)" ::: "memory");
  SD_WRITE(0);
  __syncthreads();

  int cur = 0;
  for (int t = 0; t < SDIM/32; ++t) {
    if (t + 1 < SDIM/32) SD_ISSUE(t + 1, cur ^ 1);
    bf16x8 a[4], b[4];
    #pragma unroll
    for (int m = 0; m < 4; ++m)
      a[m] = *(const bf16x8*)&A[cur][(wr*64 + m*16 + lm)*32 + (lg ^ asw)*8];
    #pragma unroll
    for (int n = 0; n < 4; ++n) {
      int row = wc*64 + n*16 + lm;
      b[n] = *(const bf16x8*)&Bd[cur][b_roff(row, lg)];
    }
    #pragma unroll
    for (int m = 0; m < 4; ++m)
      #pragma unroll
      for (int n = 0; n < 4; ++n)
        acc[m][n] = __builtin_amdgcn_mfma_f32_16x16x32_bf16(a[m], b[n], acc[m][n], 0, 0, 0);
    if (t + 1 < SDIM/32) {
      asm volatile("s_waitcnt vmcnt(0)" ::: "memory");
      SD_WRITE(cur ^ 1);
    }
    __syncthreads();
    cur ^= 1;
  }
  #undef SD_ISSUE
  #undef SD_WRITE

  #pragma unroll
  for (int m = 0; m < 4; ++m) {
    #pragma unroll
    for (int j = 0; j < 4; ++j) {
      int rl = wr*64 + m*16 + lg*4 + j;
      size_t base = (size_t)(m0 + rl) * HD + n0 + wc*64;
      #pragma unroll
      for (int n = 0; n < 4; ++n) {
        size_t idx = base + n*16 + lm;
        y[idx] += acc[m][n][j];
      }
    }
  }
}

// ---------------- launch ----------------
extern "C" void kernel_launch(void* const* d_in, const int* in_sizes, int n_in,
                              void* d_out, int out_size, void* d_ws, size_t ws_size,
                              hipStream_t stream) {
  const float* x     = (const float*)d_in[0];
  const float* wgate = (const float*)d_in[1];
  const float* wg    = (const float*)d_in[2];
  const float* wu    = (const float*)d_in[3];
  const float* wd    = (const float*)d_in[4];
  const float* sg    = (const float*)d_in[5];
  const float* su    = (const float*)d_in[6];
  const float* sd    = (const float*)d_in[7];
  float* y = (float*)d_out;
  char* ws = (char*)d_ws;

  ushort* xb   = (ushort*)(ws + 0);          // 8,388,608
  ushort* act  = (ushort*)(ws + 8388608);    // 25,165,824
  ushort* sact = (ushort*)(ws + 33554432);   // 8,388,608
  int*    tidx = (int*)  (ws + 41943040);
  float*  tw   = (float*)(ws + 41992192);
  int*    ptok = (int*)  (ws + 42041344);
  float*  pw   = (float*)(ws + 42090496);
  int*    cnt  = (int*)  (ws + 42139648);
  int*    cur  = (int*)  (ws + 42139776);
  int*    offs = (int*)  (ws + 42139904);

  hipMemsetAsync(cnt, 0, 512, stream);
  hipMemsetAsync(d_out, 0, (size_t)TT * HD * 4, stream);

  cvt_kernel<<<dim3(4096), dim3(256), 0, stream>>>(x, xb);
  gating_kernel<<<dim3(TT), dim3(64), 0, stream>>>(x, wgate, tidx, tw, cnt);
  scan_kernel<<<dim3(1), dim3(64), 0, stream>>>(cnt, offs);
  fill_kernel<<<dim3(48), dim3(256), 0, stream>>>(tidx, tw, offs, cur, ptok, pw);
  gu_routed<<<dim3(8192), dim3(256), 0, stream>>>(xb, wg, wu, ptok, pw, cnt, offs, act);
  down_routed<<<dim3(8192), dim3(256), 0, stream>>>(act, wd, ptok, cnt, offs, y);
  shared_gu<<<dim3(512), dim3(256), 0, stream>>>(xb, sg, su, sact);
  shared_down<<<dim3(256), dim3(256), 0, stream>>>(sact, sd, y);
}

// Round 4
// 801.511 us; speedup vs baseline: 1.1792x; 1.1792x over previous
//
#include <hip/hip_runtime.h>

#define HD   2048
#define FD   1024
#define NEXP 32
#define TOPK 6
#define TT   2048
#define SDIM 2048
#define NPAIR (TT*TOPK)
#define BSTR 40     // B-tile LDS row stride in ushorts (80B, 16B-aligned)

typedef __bf16 bf16x8 __attribute__((ext_vector_type(8)));
typedef float  f32x4  __attribute__((ext_vector_type(4)));

#define GLOAD_LDS16(g, l) __builtin_amdgcn_global_load_lds( \
    (const __attribute__((address_space(1))) void*)(g),     \
    (__attribute__((address_space(3))) void*)(l), 16, 0, 0)

__device__ __forceinline__ ushort f2b(float f) {
  __bf16 h = (__bf16)f;                 // native cast -> v_cvt_pk_bf16_f32 pairs
  union { __bf16 h; ushort u; } v; v.h = h;
  return v.u;
}

// row permutation for B tiles: breaks per-instruction constant row&3 on the
// transposed write (16 distinct start banks instead of 8/4) while staying
// injective mod 8 so the stride-40 read spread is unchanged.
__device__ __forceinline__ int prow(int r) {
  return (r & ~3) | ((r + (r >> 2)) & 3);
}

// ---------------- gating (fp32 exact) ----------------
__device__ __forceinline__ void argmax32(float &v, int &i) {
  #pragma unroll
  for (int m = 16; m >= 1; m >>= 1) {
    float ov = __shfl_xor(v, m, 32);
    int   oi = __shfl_xor(i, m, 32);
    if (ov > v || (ov == v && oi < i)) { v = ov; i = oi; }
  }
}

__global__ __launch_bounds__(64) void gating_kernel(
    const float* __restrict__ x, const float* __restrict__ wgate,
    int* __restrict__ topk_idx, float* __restrict__ topk_w, int* __restrict__ cnt)
{
  int t = blockIdx.x;
  int l = threadIdx.x;
  int e = l & 31;
  int half = l >> 5;
  const float* xr = x + (size_t)t * HD + half * (HD/2);
  const float* wr = wgate + (size_t)e * HD + half * (HD/2);
  float acc = 0.f;
  for (int i = 0; i < HD/2; i += 4) {
    float4 a = *(const float4*)(xr + i);
    float4 b = *(const float4*)(wr + i);
    acc += a.x*b.x + a.y*b.y + a.z*b.z + a.w*b.w;
  }
  acc += __shfl_xor(acc, 32);
  float logit = acc;
  float mx = logit;
  #pragma unroll
  for (int m = 16; m >= 1; m >>= 1) mx = fmaxf(mx, __shfl_xor(mx, m, 32));
  float p = __expf(logit - mx);
  float s = p;
  #pragma unroll
  for (int m = 16; m >= 1; m >>= 1) s += __shfl_xor(s, m, 32);
  float score = p / s;
  float gs = score;
  gs = fmaxf(gs, __shfl_xor(gs, 1, 32));
  gs = fmaxf(gs, __shfl_xor(gs, 2, 32));
  int g = e >> 2;
  float gw = gs;
  bool ingroup = false;
  for (int r = 0; r < 3; ++r) {
    float v = gw; int gi = g;
    argmax32(v, gi);
    if (g == gi) { ingroup = true; gw = -1.f; }
  }
  float ms = ingroup ? score : 0.f;
  int myrank = -1;
  float denom = 1e-20f;
  float mw = ms;
  for (int r = 0; r < 6; ++r) {
    float v = mw; int ei = e;
    argmax32(v, ei);
    denom += v;
    if (e == ei) { myrank = r; mw = -1.f; }
  }
  if (l < 32 && myrank >= 0) {
    topk_idx[t*TOPK + myrank] = e;
    topk_w  [t*TOPK + myrank] = score / denom;
    atomicAdd(&cnt[e], 1);
  }
}

__global__ void scan_kernel(const int* __restrict__ cnt, int* __restrict__ offs) {
  if (threadIdx.x == 0) {
    int o = 0;
    for (int e = 0; e < NEXP; ++e) { offs[e] = o; o += cnt[e]; }
  }
}

__global__ void fill_kernel(const int* __restrict__ topk_idx, const float* __restrict__ topk_w,
                            const int* __restrict__ offs, int* __restrict__ cur,
                            int* __restrict__ pair_tok, float* __restrict__ pair_w)
{
  int idx = blockIdx.x * blockDim.x + threadIdx.x;
  if (idx >= NPAIR) return;
  int e = topk_idx[idx];
  int p = offs[e] + atomicAdd(&cur[e], 1);
  pair_tok[p] = idx / TOPK;
  pair_w[p]   = topk_w[idx];
}

__global__ void cvt_kernel(const float* __restrict__ x, ushort* __restrict__ xb) {
  int i = blockIdx.x * blockDim.x + threadIdx.x;
  float4 v = ((const float4*)x)[i];
  ((ushort4*)xb)[i] = make_ushort4(f2b(v.x), f2b(v.y), f2b(v.z), f2b(v.w));
}

// ---------------- routed gate+up: BM=128 BN=64(x2) BK=32, dbuf ----------------
__global__ __launch_bounds__(256) void gu_routed(
    const ushort* __restrict__ xb, const float* __restrict__ wg, const float* __restrict__ wu,
    const int* __restrict__ pair_tok, const float* __restrict__ pair_w,
    const int* __restrict__ cnt, const int* __restrict__ offs,
    ushort* __restrict__ act)
{
  __shared__ ushort A[2][128*32];
  __shared__ ushort Bg[2][64*BSTR];
  __shared__ ushort Bu[2][64*BSTR];

  int bid = blockIdx.x;
  int wid = (bid & 7) * 1024 + (bid >> 3);   // XCD chunk swizzle (8192/8)
  int mt = wid & 15;
  int nt = (wid >> 4) & 15;
  int e  = wid >> 8;
  int ce = cnt[e];
  int m0 = mt * 128;
  if (m0 >= ce) return;
  int oe = offs[e];
  int n0 = nt * 64;
  int tid = threadIdx.x, lane = tid & 63, w = tid >> 6;

  int csrc = (lane & 3) ^ ((lane >> 3) & 3);
  const ushort* asrc[2];
  #pragma unroll
  for (int j = 0; j < 2; ++j) {
    int r = (2*w + j)*16 + (lane >> 2);
    int pi = min(m0 + r, ce - 1);
    asrc[j] = xb + (size_t)pair_tok[oe + pi] * HD + csrc * 8;
  }
  int tsel = tid >> 7;
  int ttb = tid & 127;
  int fg = ttb & 15, hg = ttb >> 4;
  const float* wsrc = (tsel ? wu : wg) + (size_t)e * HD * FD + (size_t)hg*4*FD + n0 + fg*4;

  int lm = lane & 15, lg = lane >> 4;
  int wr = w >> 1, wc = w & 1;
  int asw = (lm >> 1) & 3;

  f32x4 accg[4][2], accu[4][2];
  #pragma unroll
  for (int m = 0; m < 4; ++m)
    #pragma unroll
    for (int n = 0; n < 2; ++n) { accg[m][n] = f32x4{0,0,0,0}; accu[m][n] = f32x4{0,0,0,0}; }

  float4 rB[4];
  #define GU_ISSUE(T, BUF) do { \
    _Pragma("unroll") \
    for (int j = 0; j < 2; ++j) \
      GLOAD_LDS16(asrc[j] + (T)*32, &A[BUF][(2*w+j)*512]); \
    const float* p = wsrc + (size_t)(T)*32*FD; \
    rB[0] = *(const float4*)(p); \
    rB[1] = *(const float4*)(p + FD); \
    rB[2] = *(const float4*)(p + 2*FD); \
    rB[3] = *(const float4*)(p + 3*FD); \
  } while (0)
  #define GU_WRITE(BUF) do { \
    ushort* dst = tsel ? &Bu[BUF][0] : &Bg[BUF][0]; \
    _Pragma("unroll") \
    for (int c = 0; c < 4; ++c) { \
      int row = fg*4 + ((c + fg) & 3); \
      *(ushort4*)&dst[row*BSTR + hg*4] = \
        make_ushort4(f2b(rB[0][c]), f2b(rB[1][c]), f2b(rB[2][c]), f2b(rB[3][c])); \
    } \
  } while (0)

  GU_ISSUE(0, 0);
  asm volatile("s_waitcnt vmcnt(0)" ::: "memory");
  GU_WRITE(0);
  __syncthreads();

  int cur = 0;
  for (int t = 0; t < HD/32; ++t) {
    if (t + 1 < HD/32) GU_ISSUE(t + 1, cur ^ 1);
    bf16x8 a[4], bg[2], bu[2];
    #pragma unroll
    for (int m = 0; m < 4; ++m)
      a[m] = *(const bf16x8*)&A[cur][(wr*64 + m*16 + lm)*32 + (lg ^ asw)*8];
    #pragma unroll
    for (int n = 0; n < 2; ++n) {
      int row = prow(wc*32 + n*16 + lm);
      bg[n] = *(const bf16x8*)&Bg[cur][row*BSTR + lg*8];
      bu[n] = *(const bf16x8*)&Bu[cur][row*BSTR + lg*8];
    }
    #pragma unroll
    for (int m = 0; m < 4; ++m)
      #pragma unroll
      for (int n = 0; n < 2; ++n) {
        accg[m][n] = __builtin_amdgcn_mfma_f32_16x16x32_bf16(a[m], bg[n], accg[m][n], 0, 0, 0);
        accu[m][n] = __builtin_amdgcn_mfma_f32_16x16x32_bf16(a[m], bu[n], accu[m][n], 0, 0, 0);
      }
    if (t + 1 < HD/32) {
      asm volatile("s_waitcnt vmcnt(0)" ::: "memory");
      GU_WRITE(cur ^ 1);
    }
    __syncthreads();
    cur ^= 1;
  }
  #undef GU_ISSUE
  #undef GU_WRITE

  #pragma unroll
  for (int m = 0; m < 4; ++m) {
    #pragma unroll
    for (int j = 0; j < 4; ++j) {
      int rl = wr*64 + m*16 + lg*4 + j;
      int pi = m0 + rl;
      if (pi >= ce) continue;
      float pwv = pair_w[oe + pi];
      size_t base = (size_t)(oe + pi) * FD + n0 + wc*32;
      #pragma unroll
      for (int n = 0; n < 2; ++n) {
        float gv = accg[m][n][j];
        float uv = accu[m][n][j];
        float sv = gv / (1.f + __expf(-gv));
        act[base + n*16 + lm] = f2b(sv * uv * pwv);
      }
    }
  }
}

// ---------------- routed down: BM=128 BN=128 BK=32, dbuf, atomic scatter ----------------
__global__ __launch_bounds__(256) void down_routed(
    const ushort* __restrict__ act, const float* __restrict__ wd,
    const int* __restrict__ pair_tok, const int* __restrict__ cnt, const int* __restrict__ offs,
    float* __restrict__ y)
{
  __shared__ ushort A[2][128*32];
  __shared__ ushort Bd[2][128*BSTR];

  int bid = blockIdx.x;
  int wid = (bid & 7) * 1024 + (bid >> 3);
  int mt = wid & 15;
  int nt = (wid >> 4) & 15;
  int e  = wid >> 8;
  int ce = cnt[e];
  int m0 = mt * 128;
  if (m0 >= ce) return;
  int oe = offs[e];
  int n0 = nt * 128;
  int tid = threadIdx.x, lane = tid & 63, w = tid >> 6;

  int csrc = (lane & 3) ^ ((lane >> 3) & 3);
  const ushort* asrc[2];
  #pragma unroll
  for (int j = 0; j < 2; ++j) {
    int r = (2*w + j)*16 + (lane >> 2);
    int pi = min(m0 + r, ce - 1);
    asrc[j] = act + (size_t)(oe + pi) * FD + csrc * 8;
  }
  int fg = tid & 31, hg = tid >> 5;
  const float* wsrc = wd + (size_t)e * FD * HD + (size_t)hg*4*HD + n0 + fg*4;

  int lm = lane & 15, lg = lane >> 4;
  int wr = w >> 1, wc = w & 1;
  int asw = (lm >> 1) & 3;

  f32x4 acc[4][4];
  #pragma unroll
  for (int m = 0; m < 4; ++m)
    #pragma unroll
    for (int n = 0; n < 4; ++n) acc[m][n] = f32x4{0,0,0,0};

  float4 rB[4];
  #define DN_ISSUE(T, BUF) do { \
    _Pragma("unroll") \
    for (int j = 0; j < 2; ++j) \
      GLOAD_LDS16(asrc[j] + (T)*32, &A[BUF][(2*w+j)*512]); \
    const float* p = wsrc + (size_t)(T)*32*HD; \
    rB[0] = *(const float4*)(p); \
    rB[1] = *(const float4*)(p + HD); \
    rB[2] = *(const float4*)(p + 2*HD); \
    rB[3] = *(const float4*)(p + 3*HD); \
  } while (0)
  #define DN_WRITE(BUF) do { \
    _Pragma("unroll") \
    for (int c = 0; c < 4; ++c) { \
      int row = fg*4 + ((c + fg) & 3); \
      *(ushort4*)&Bd[BUF][row*BSTR + hg*4] = \
        make_ushort4(f2b(rB[0][c]), f2b(rB[1][c]), f2b(rB[2][c]), f2b(rB[3][c])); \
    } \
  } while (0)

  DN_ISSUE(0, 0);
  asm volatile("s_waitcnt vmcnt(0)" ::: "memory");
  DN_WRITE(0);
  __syncthreads();

  int cur = 0;
  for (int t = 0; t < FD/32; ++t) {
    if (t + 1 < FD/32) DN_ISSUE(t + 1, cur ^ 1);
    bf16x8 a[4], b[4];
    #pragma unroll
    for (int m = 0; m < 4; ++m)
      a[m] = *(const bf16x8*)&A[cur][(wr*64 + m*16 + lm)*32 + (lg ^ asw)*8];
    #pragma unroll
    for (int n = 0; n < 4; ++n) {
      int row = prow(wc*64 + n*16 + lm);
      b[n] = *(const bf16x8*)&Bd[cur][row*BSTR + lg*8];
    }
    #pragma unroll
    for (int m = 0; m < 4; ++m)
      #pragma unroll
      for (int n = 0; n < 4; ++n)
        acc[m][n] = __builtin_amdgcn_mfma_f32_16x16x32_bf16(a[m], b[n], acc[m][n], 0, 0, 0);
    if (t + 1 < FD/32) {
      asm volatile("s_waitcnt vmcnt(0)" ::: "memory");
      DN_WRITE(cur ^ 1);
    }
    __syncthreads();
    cur ^= 1;
  }
  #undef DN_ISSUE
  #undef DN_WRITE

  #pragma unroll
  for (int m = 0; m < 4; ++m) {
    #pragma unroll
    for (int j = 0; j < 4; ++j) {
      int rl = wr*64 + m*16 + lg*4 + j;
      int pi = m0 + rl;
      if (pi >= ce) continue;
      int tok = pair_tok[oe + pi];
      size_t base = (size_t)tok * HD + n0 + wc*64;
      #pragma unroll
      for (int n = 0; n < 4; ++n)
        atomicAdd(&y[base + n*16 + lm], acc[m][n][j]);
    }
  }
}

// ---------------- shared gate+up: BM=128 BN=64(x2) BK=32, dbuf ----------------
__global__ __launch_bounds__(256) void shared_gu(
    const ushort* __restrict__ xb, const float* __restrict__ sg, const float* __restrict__ su,
    ushort* __restrict__ sact)
{
  __shared__ ushort A[2][128*32];
  __shared__ ushort Bg[2][64*BSTR];
  __shared__ ushort Bu[2][64*BSTR];

  int bid = blockIdx.x;
  int wid = (bid & 7) * 64 + (bid >> 3);
  int mt = wid & 15;
  int nt = wid >> 4;
  int m0 = mt * 128;
  int n0 = nt * 64;
  int tid = threadIdx.x, lane = tid & 63, w = tid >> 6;

  int csrc = (lane & 3) ^ ((lane >> 3) & 3);
  const ushort* asrc[2];
  #pragma unroll
  for (int j = 0; j < 2; ++j) {
    int r = (2*w + j)*16 + (lane >> 2);
    asrc[j] = xb + (size_t)(m0 + r) * HD + csrc * 8;
  }
  int tsel = tid >> 7;
  int ttb = tid & 127;
  int bn = ttb >> 1, bsub = ttb & 1;       // row (n), k-half of 16 floats
  const float* bsrc = (tsel ? su : sg) + (size_t)(n0 + bn) * HD + bsub * 16;

  int lm = lane & 15, lg = lane >> 4;
  int wr = w >> 1, wc = w & 1;
  int asw = (lm >> 1) & 3;

  f32x4 accg[4][2], accu[4][2];
  #pragma unroll
  for (int m = 0; m < 4; ++m)
    #pragma unroll
    for (int n = 0; n < 2; ++n) { accg[m][n] = f32x4{0,0,0,0}; accu[m][n] = f32x4{0,0,0,0}; }

  float4 rB[4];
  #define SG_ISSUE(T, BUF) do { \
    _Pragma("unroll") \
    for (int j = 0; j < 2; ++j) \
      GLOAD_LDS16(asrc[j] + (T)*32, &A[BUF][(2*w+j)*512]); \
    const float* p = bsrc + (T)*32; \
    rB[0] = *(const float4*)(p); \
    rB[1] = *(const float4*)(p + 4); \
    rB[2] = *(const float4*)(p + 8); \
    rB[3] = *(const float4*)(p + 12); \
  } while (0)
  #define SG_WRITE(BUF) do { \
    ushort* dst = (tsel ? &Bu[BUF][0] : &Bg[BUF][0]) + bn*BSTR + bsub*16; \
    dst[0]=f2b(rB[0][0]); dst[1]=f2b(rB[0][1]); dst[2]=f2b(rB[0][2]); dst[3]=f2b(rB[0][3]); \
    dst[4]=f2b(rB[1][0]); dst[5]=f2b(rB[1][1]); dst[6]=f2b(rB[1][2]); dst[7]=f2b(rB[1][3]); \
    dst[8]=f2b(rB[2][0]); dst[9]=f2b(rB[2][1]); dst[10]=f2b(rB[2][2]); dst[11]=f2b(rB[2][3]); \
    dst[12]=f2b(rB[3][0]); dst[13]=f2b(rB[3][1]); dst[14]=f2b(rB[3][2]); dst[15]=f2b(rB[3][3]); \
  } while (0)

  SG_ISSUE(0, 0);
  asm volatile("s_waitcnt vmcnt(0)" ::: "memory");
  SG_WRITE(0);
  __syncthreads();

  int cur = 0;
  for (int t = 0; t < HD/32; ++t) {
    if (t + 1 < HD/32) SG_ISSUE(t + 1, cur ^ 1);
    bf16x8 a[4], bg[2], bu[2];
    #pragma unroll
    for (int m = 0; m < 4; ++m)
      a[m] = *(const bf16x8*)&A[cur][(wr*64 + m*16 + lm)*32 + (lg ^ asw)*8];
    #pragma unroll
    for (int n = 0; n < 2; ++n) {
      int row = wc*32 + n*16 + lm;
      bg[n] = *(const bf16x8*)&Bg[cur][row*BSTR + lg*8];
      bu[n] = *(const bf16x8*)&Bu[cur][row*BSTR + lg*8];
    }
    #pragma unroll
    for (int m = 0; m < 4; ++m)
      #pragma unroll
      for (int n = 0; n < 2; ++n) {
        accg[m][n] = __builtin_amdgcn_mfma_f32_16x16x32_bf16(a[m], bg[n], accg[m][n], 0, 0, 0);
        accu[m][n] = __builtin_amdgcn_mfma_f32_16x16x32_bf16(a[m], bu[n], accu[m][n], 0, 0, 0);
      }
    if (t + 1 < HD/32) {
      asm volatile("s_waitcnt vmcnt(0)" ::: "memory");
      SG_WRITE(cur ^ 1);
    }
    __syncthreads();
    cur ^= 1;
  }
  #undef SG_ISSUE
  #undef SG_WRITE

  #pragma unroll
  for (int m = 0; m < 4; ++m) {
    #pragma unroll
    for (int j = 0; j < 4; ++j) {
      int rl = wr*64 + m*16 + lg*4 + j;
      size_t base = (size_t)(m0 + rl) * SDIM + n0 + wc*32;
      #pragma unroll
      for (int n = 0; n < 2; ++n) {
        float gv = accg[m][n][j];
        float uv = accu[m][n][j];
        float sv = gv / (1.f + __expf(-gv));
        sact[base + n*16 + lm] = f2b(sv * uv);
      }
    }
  }
}

// ---------------- shared down: BM=128 BN=128 BK=32, dbuf, y += ----------------
__global__ __launch_bounds__(256) void shared_down(
    const ushort* __restrict__ sact, const float* __restrict__ sd, float* __restrict__ y)
{
  __shared__ ushort A[2][128*32];
  __shared__ ushort Bd[2][128*BSTR];

  int bid = blockIdx.x;
  int wid = (bid & 7) * 32 + (bid >> 3);
  int mt = wid & 15;
  int nt = wid >> 4;
  int m0 = mt * 128;
  int n0 = nt * 128;
  int tid = threadIdx.x, lane = tid & 63, w = tid >> 6;

  int csrc = (lane & 3) ^ ((lane >> 3) & 3);
  const ushort* asrc[2];
  #pragma unroll
  for (int j = 0; j < 2; ++j) {
    int r = (2*w + j)*16 + (lane >> 2);
    asrc[j] = sact + (size_t)(m0 + r) * SDIM + csrc * 8;
  }
  int bn = tid >> 1, bsub = tid & 1;
  const float* bsrc = sd + (size_t)(n0 + bn) * SDIM + bsub * 16;

  int lm = lane & 15, lg = lane >> 4;
  int wr = w >> 1, wc = w & 1;
  int asw = (lm >> 1) & 3;

  f32x4 acc[4][4];
  #pragma unroll
  for (int m = 0; m < 4; ++m)
    #pragma unroll
    for (int n = 0; n < 4; ++n) acc[m][n] = f32x4{0,0,0,0};

  float4 rB[4];
  #define SD_ISSUE(T, BUF) do { \
    _Pragma("unroll") \
    for (int j = 0; j < 2; ++j) \
      GLOAD_LDS16(asrc[j] + (T)*32, &A[BUF][(2*w+j)*512]); \
    const float* p = bsrc + (T)*32; \
    rB[0] = *(const float4*)(p); \
    rB[1] = *(const float4*)(p + 4); \
    rB[2] = *(const float4*)(p + 8); \
    rB[3] = *(const float4*)(p + 12); \
  } while (0)
  #define SD_WRITE(BUF) do { \
    ushort* dst = &Bd[BUF][bn*BSTR + bsub*16]; \
    dst[0]=f2b(rB[0][0]); dst[1]=f2b(rB[0][1]); dst[2]=f2b(rB[0][2]); dst[3]=f2b(rB[0][3]); \
    dst[4]=f2b(rB[1][0]); dst[5]=f2b(rB[1][1]); dst[6]=f2b(rB[1][2]); dst[7]=f2b(rB[1][3]); \
    dst[8]=f2b(rB[2][0]); dst[9]=f2b(rB[2][1]); dst[10]=f2b(rB[2][2]); dst[11]=f2b(rB[2][3]); \
    dst[12]=f2b(rB[3][0]); dst[13]=f2b(rB[3][1]); dst[14]=f2b(rB[3][2]); dst[15]=f2b(rB[3][3]); \
  } while (0)

  SD_ISSUE(0, 0);
  asm volatile("s_waitcnt vmcnt(0)" ::: "memory");
  SD_WRITE(0);
  __syncthreads();

  int cur = 0;
  for (int t = 0; t < SDIM/32; ++t) {
    if (t + 1 < SDIM/32) SD_ISSUE(t + 1, cur ^ 1);
    bf16x8 a[4], b[4];
    #pragma unroll
    for (int m = 0; m < 4; ++m)
      a[m] = *(const bf16x8*)&A[cur][(wr*64 + m*16 + lm)*32 + (lg ^ asw)*8];
    #pragma unroll
    for (int n = 0; n < 4; ++n) {
      int row = wc*64 + n*16 + lm;
      b[n] = *(const bf16x8*)&Bd[cur][row*BSTR + lg*8];
    }
    #pragma unroll
    for (int m = 0; m < 4; ++m)
      #pragma unroll
      for (int n = 0; n < 4; ++n)
        acc[m][n] = __builtin_amdgcn_mfma_f32_16x16x32_bf16(a[m], b[n], acc[m][n], 0, 0, 0);
    if (t + 1 < SDIM/32) {
      asm volatile("s_waitcnt vmcnt(0)" ::: "memory");
      SD_WRITE(cur ^ 1);
    }
    __syncthreads();
    cur ^= 1;
  }
  #undef SD_ISSUE
  #undef SD_WRITE

  #pragma unroll
  for (int m = 0; m < 4; ++m) {
    #pragma unroll
    for (int j = 0; j < 4; ++j) {
      int rl = wr*64 + m*16 + lg*4 + j;
      size_t base = (size_t)(m0 + rl) * HD + n0 + wc*64;
      #pragma unroll
      for (int n = 0; n < 4; ++n) {
        size_t idx = base + n*16 + lm;
        y[idx] += acc[m][n][j];
      }
    }
  }
}

// ---------------- launch ----------------
extern "C" void kernel_launch(void* const* d_in, const int* in_sizes, int n_in,
                              void* d_out, int out_size, void* d_ws, size_t ws_size,
                              hipStream_t stream) {
  const float* x     = (const float*)d_in[0];
  const float* wgate = (const float*)d_in[1];
  const float* wg    = (const float*)d_in[2];
  const float* wu    = (const float*)d_in[3];
  const float* wd    = (const float*)d_in[4];
  const float* sg    = (const float*)d_in[5];
  const float* su    = (const float*)d_in[6];
  const float* sd    = (const float*)d_in[7];
  float* y = (float*)d_out;
  char* ws = (char*)d_ws;

  ushort* xb   = (ushort*)(ws + 0);          // 8,388,608
  ushort* act  = (ushort*)(ws + 8388608);    // 25,165,824
  ushort* sact = (ushort*)(ws + 33554432);   // 8,388,608
  int*    tidx = (int*)  (ws + 41943040);
  float*  tw   = (float*)(ws + 41992192);
  int*    ptok = (int*)  (ws + 42041344);
  float*  pw   = (float*)(ws + 42090496);
  int*    cnt  = (int*)  (ws + 42139648);
  int*    cur  = (int*)  (ws + 42139776);
  int*    offs = (int*)  (ws + 42139904);

  hipMemsetAsync(cnt, 0, 512, stream);
  hipMemsetAsync(d_out, 0, (size_t)TT * HD * 4, stream);

  cvt_kernel<<<dim3(4096), dim3(256), 0, stream>>>(x, xb);
  gating_kernel<<<dim3(TT), dim3(64), 0, stream>>>(x, wgate, tidx, tw, cnt);
  scan_kernel<<<dim3(1), dim3(64), 0, stream>>>(cnt, offs);
  fill_kernel<<<dim3(48), dim3(256), 0, stream>>>(tidx, tw, offs, cur, ptok, pw);
  gu_routed<<<dim3(8192), dim3(256), 0, stream>>>(xb, wg, wu, ptok, pw, cnt, offs, act);
  down_routed<<<dim3(8192), dim3(256), 0, stream>>>(act, wd, ptok, cnt, offs, y);
  shared_gu<<<dim3(512), dim3(256), 0, stream>>>(xb, sg, su, sact);
  shared_down<<<dim3(256), dim3(256), 0, stream>>>(sact, sd, y);
}